// Round 8
// baseline (50.148 us; speedup 1.0000x reference)
//
#include <hip/hip_runtime.h>
#include <math.h>

#define NB 256
#define NV 2
#define NN 512
#define ND 10
#define THRESH_SQ 6.0f
#define EPS_W 1e-6f

typedef __attribute__((ext_vector_type(8))) short bf16x8;
typedef __attribute__((ext_vector_type(4))) float f32x4;

__device__ __forceinline__ unsigned short f2bf(float x) {
    union { float f; unsigned u; } v; v.f = x;
    unsigned r = v.u + 0x7FFFu + ((v.u >> 16) & 1u);   // RNE
    return (unsigned short)(r >> 16);
}
__device__ __forceinline__ float bf2f(unsigned short h) {
    union { unsigned u; float f; } v; v.u = ((unsigned)h) << 16; return v.f;
}
__device__ __forceinline__ void split3(float x, unsigned short* s) {
    unsigned short h = f2bf(x); float r = x - bf2f(h);
    unsigned short m = f2bf(r); float r2 = r - bf2f(m);
    s[0] = h; s[1] = m; s[2] = f2bf(r2);
}
__device__ __forceinline__ unsigned umin_(unsigned a, unsigned b) { return a < b ? a : b; }

// chunk-major record layout, XOR-swizzled; byte offset within the 32KB buffer
__device__ __forceinline__ int recaddr(int c, int row) {
    return (c << 13) + ((row << 4) ^ (c << 5));
}

// One block (512 thr) per bv. P (+2^-10 bias) via bf16-split MFMA; both argmin
// axes tracked as packed u32 keys (value-high-bits | index). Col-axis per-mt
// reduction is a balanced tree in NAMED SCALARS (a ck[16] array gets demoted
// to scratch: round 7, FETCH 14->39MB WRITE->73MB, dur 30.7->47.6us). bfr is
// software-prefetched one mt ahead to hide LDS->MFMA latency.
// NOTE: launch_bounds min-waves MUST stay <=6 — 8 forces a 64-VGPR cap and the
// kernel spills to scratch (round 5: FETCH 14MB->201MB, dur 32->112us).
__global__ __launch_bounds__(512, 6)
void chamfer_bv(const float* __restrict__ achieved,
                const float* __restrict__ desired,
                float* __restrict__ rv_out)
{
    const int bv  = blockIdx.x;
    const int tid = threadIdx.x;

    __shared__ __align__(16) char buf[32768];     // A records, then B records,
                                                  // then rowKeyArr/cnt/red overlay
    __shared__ unsigned colKey[NN * 2];           // [m][lchk>>1]

    const float* arow = achieved + ((size_t)bv * NN + tid) * ND;
    const float* drow = desired  + ((size_t)bv * NN + tid) * ND;

    const unsigned short ONE = 0x3F80;
    const int pi[6] = {0,0,1,2,1,0};   // split-product pairs with i+j<=2
    const int pj[6] = {0,1,0,0,1,2};

    const float g5 = drow[5], g6 = drow[6], g7 = drow[7], g8 = drow[8];

    // ---- phase 1: A records (achieved; -2-scaled splits + sn2 + ONEs) ----
    {
        float a5 = arow[5], a6 = arow[6], a7 = arow[7], a8 = arow[8];
        unsigned short us[4][3];
        split3(-2.0f*a5, us[0]); split3(-2.0f*a6, us[1]);
        split3(-2.0f*a7, us[2]); split3(-2.0f*a8, us[3]);
        float sn2 = a5*a5 + a6*a6 + a7*a7 + a8*a8;
        unsigned short sn[3]; split3(sn2, sn);
        unsigned short t[32];
        #pragma unroll
        for (int d = 0; d < 4; ++d)
            #pragma unroll
            for (int p = 0; p < 6; ++p)
                t[d*6+p] = us[d][pi[p]];
        t[24]=sn[0]; t[25]=sn[1]; t[26]=sn[2];
        t[27]=ONE;   t[28]=ONE;   t[29]=ONE;
        t[30]=ONE;   t[31]=0;                       // pairs with bias in B
        #pragma unroll
        for (int c = 0; c < 4; ++c) {
            bf16x8 v;
            #pragma unroll
            for (int e = 0; e < 8; ++e) v[e] = (short)t[c*8+e];
            *(bf16x8*)(buf + recaddr(c, tid)) = v;
        }
    }
    colKey[tid*2]   = 0xFFFFFFFFu;
    colKey[tid*2+1] = 0xFFFFFFFFu;
    __syncthreads();

    const int lane = tid & 63, wid = tid >> 6;
    const int lrow = lane & 15, lchk = lane >> 4;

    bf16x8 afr[4];
    #pragma unroll
    for (int nt = 0; nt < 4; ++nt)
        afr[nt] = *(const bf16x8*)(buf + recaddr(lchk, (wid<<6) + (nt<<4) + lrow));
    __syncthreads();   // A region dead

    // ---- phase 2: B records (desired) overwrite the same buffer ----
    {
        unsigned short gs[4][3];
        split3(g5, gs[0]); split3(g6, gs[1]); split3(g7, gs[2]); split3(g8, gs[3]);
        float gn2 = g5*g5 + g6*g6 + g7*g7 + g8*g8;
        unsigned short gn[3]; split3(gn2, gn);
        unsigned short t[32];
        #pragma unroll
        for (int d = 0; d < 4; ++d)
            #pragma unroll
            for (int p = 0; p < 6; ++p)
                t[d*6+p] = gs[d][pj[p]];
        t[24]=ONE;   t[25]=ONE;   t[26]=ONE;
        t[27]=gn[0]; t[28]=gn[1]; t[29]=gn[2];
        t[30]=0x3A80; t[31]=0;                      // +2^-10 bias -> P strictly > 0
        #pragma unroll
        for (int c = 0; c < 4; ++c) {
            bf16x8 v;
            #pragma unroll
            for (int e = 0; e < 8; ++e) v[e] = (short)t[c*8+e];
            *(bf16x8*)(buf + recaddr(c, tid)) = v;
        }
    }
    __syncthreads();

    unsigned rowKey[4][4];
    int ncst[4][4];
    #pragma unroll
    for (int nt = 0; nt < 4; ++nt)
        #pragma unroll
        for (int j = 0; j < 4; ++j) {
            rowKey[nt][j] = 0xFFFFFFFFu;
            ncst[nt][j]   = (wid<<6) + (nt<<4) + (lchk<<2) + j;
        }

    const unsigned MASK = 0xFFFFFE00u;
    const f32x4 z = {0.0f, 0.0f, 0.0f, 0.0f};
    const int cslice = lchk >> 1;

    // ---- main loop: 32 m-tiles; prefetched bfr; scalar min-tree for col ----
    bf16x8 bfr = *(const bf16x8*)(buf + recaddr(lchk, lrow));   // mt = 0
    #pragma unroll 4
    for (int mt = 0; mt < 32; ++mt) {
        const int mtn = (mt + 1) & 31;   // wrapped: branchless prefetch
        bf16x8 bnext = *(const bf16x8*)(buf + recaddr(lchk, (mtn<<4) + lrow));
        const unsigned mcur = (unsigned)((mt<<4) + lrow);
        unsigned cp0, cp1, cp2, cp3;
        #pragma unroll
        for (int nt = 0; nt < 4; ++nt) {
            f32x4 acc = __builtin_amdgcn_mfma_f32_16x16x32_bf16(afr[nt], bfr, z, 0, 0, 0);
            unsigned b0 = __float_as_uint(acc[0]) & MASK;
            unsigned b1 = __float_as_uint(acc[1]) & MASK;
            unsigned b2 = __float_as_uint(acc[2]) & MASK;
            unsigned b3 = __float_as_uint(acc[3]) & MASK;
            rowKey[nt][0] = umin_(rowKey[nt][0], b0 | mcur);
            rowKey[nt][1] = umin_(rowKey[nt][1], b1 | mcur);
            rowKey[nt][2] = umin_(rowKey[nt][2], b2 | mcur);
            rowKey[nt][3] = umin_(rowKey[nt][3], b3 | mcur);
            unsigned k0 = b0 | (unsigned)ncst[nt][0];
            unsigned k1 = b1 | (unsigned)ncst[nt][1];
            unsigned k2 = b2 | (unsigned)ncst[nt][2];
            unsigned k3 = b3 | (unsigned)ncst[nt][3];
            unsigned cp = umin_(umin_(k0, k1), umin_(k2, k3));
            if (nt == 0) cp0 = cp; else if (nt == 1) cp1 = cp;
            else if (nt == 2) cp2 = cp; else cp3 = cp;
        }
        unsigned cv = umin_(umin_(cp0, cp1), umin_(cp2, cp3));
        atomicMin(&colKey[(mcur << 1) | cslice], cv);   // 2-way same-addr max
        bfr = bnext;
    }

    // ---- row combine across the 16 lrow lanes (registers only) ----
    #pragma unroll
    for (int nt = 0; nt < 4; ++nt) {
        #pragma unroll
        for (int j = 0; j < 4; ++j) {
            unsigned v = rowKey[nt][j];
            #pragma unroll
            for (int s = 1; s <= 8; s <<= 1)
                v = umin_(v, (unsigned)__shfl_xor((int)v, s));
            rowKey[nt][j] = v;
        }
    }
    __syncthreads();   // buf dead, colKey atomics complete

    // ---- overlay post-loop arrays into buf ----
    unsigned* rowKeyArr = (unsigned*)buf;          // [512]
    int*      cnt       = (int*)(buf + 2048);      // [512]: A low16, B high16
    float*    redF      = (float*)(buf + 4096);    // [16]
    int*      redI      = (int*)(buf + 4160);      // [16]

    if (lrow == 0) {
        #pragma unroll
        for (int nt = 0; nt < 4; ++nt)
            #pragma unroll
            for (int j = 0; j < 4; ++j)
                rowKeyArr[ncst[nt][j]] = rowKey[nt][j];
    }
    cnt[tid] = 0;
    __syncthreads();

    // ---- epilogue: thread tid owns goal m=tid (dir A) and state n=tid (dir B) ----
    const unsigned kA = umin_(colKey[tid*2], colKey[tid*2+1]);
    const unsigned kB = rowKeyArr[tid];
    const int miA = (int)(kA & 0x1FFu);
    const int miB = (int)(kB & 0x1FFu);
    const bool latA = __uint_as_float(kA & MASK) > THRESH_SQ;
    const bool latB = __uint_as_float(kB & MASK) > THRESH_SQ;
    if (!latA) atomicAdd(&cnt[miA], 1);
    if (!latB) atomicAdd(&cnt[miB], 0x10000);
    __syncthreads();

    float sumA = 0.0f, sumB = 0.0f;
    if (!latA) {
        const float* sp = achieved + ((size_t)bv * NN + miA) * ND;
        float dx = drow[0] - sp[0], dy = drow[1] - sp[1];
        float w = 1.0f / ((float)(cnt[miA] & 0xFFFF) + EPS_W);
        sumA = w * sqrtf(dx*dx + dy*dy);
    }
    if (!latB) {
        const float* gp = desired + ((size_t)bv * NN + miB) * ND;
        float dx = arow[0] - gp[0], dy = arow[1] - gp[1];
        float w = 1.0f / ((float)(((unsigned)cnt[miB]) >> 16) + EPS_W);
        sumB = w * sqrtf(dx*dx + dy*dy);
    }
    const int c0 = cnt[tid];
    int grpPk = ((c0 & 0xFFFF) ? 1 : 0) | ((((unsigned)c0) >> 16) ? 0x10000 : 0);
    int latPk = (latA ? 1 : 0) | (latB ? 2 : 0);

    #pragma unroll
    for (int off = 32; off > 0; off >>= 1) {
        sumA  += __shfl_down(sumA, off);
        sumB  += __shfl_down(sumB, off);
        grpPk += __shfl_down(grpPk, off);
        latPk |= __shfl_down(latPk, off);
    }
    if (lane == 0) {
        redF[wid*2] = sumA; redF[wid*2+1] = sumB;
        redI[wid*2] = grpPk; redI[wid*2+1] = latPk;
    }
    __syncthreads();
    if (tid == 0) {
        float sA = 0.0f, sB = 0.0f; int G = 0, L = 0;
        #pragma unroll
        for (int w2 = 0; w2 < 8; ++w2) {
            sA += redF[w2*2]; sB += redF[w2*2+1];
            G  += redI[w2*2]; L |= redI[w2*2+1];
        }
        float unmA = (L & 1) ? 1.0f : 0.0f;
        float unmB = (L & 2) ? 1.0f : 0.0f;
        float gA = (float)(G & 0xFFFF), gB = (float)(((unsigned)G) >> 16);
        float rA = -(sA + unmA) / fmaxf(gA + unmA, 1.0f);
        float rB = -(sB + unmB) / fmaxf(gB + unmB, 1.0f);
        rv_out[bv] = 0.5f * (rA + rB);
    }
}

// out[b] = mean over v
__global__ void chamfer_finalize(const float* __restrict__ rv, float* __restrict__ out)
{
    int b = blockIdx.x * 256 + threadIdx.x;
    if (b < NB) out[b] = 0.5f * (rv[2*b] + rv[2*b + 1]);
}

extern "C" void kernel_launch(void* const* d_in, const int* in_sizes, int n_in,
                              void* d_out, int out_size, void* d_ws, size_t ws_size,
                              hipStream_t stream)
{
    const float* achieved = (const float*)d_in[0];
    const float* desired  = (const float*)d_in[1];
    float* out = (float*)d_out;
    float* rv  = (float*)d_ws;   // 2 KB scratch

    chamfer_bv<<<NB * NV, 512, 0, stream>>>(achieved, desired, rv);
    chamfer_finalize<<<1, 256, 0, stream>>>(rv, out);
}

// Round 9
// 30.139 us; speedup vs baseline: 1.6639x; 1.6639x over previous
//
#include <hip/hip_runtime.h>
#include <math.h>

#define NB 256
#define NV 2
#define NN 512
#define ND 10
#define THRESH_SQ 6.0f
#define EPS_W 1e-6f

typedef __attribute__((ext_vector_type(8))) short bf16x8;
typedef __attribute__((ext_vector_type(4))) float f32x4;

__device__ __forceinline__ unsigned short f2bf(float x) {
    union { float f; unsigned u; } v; v.f = x;
    unsigned r = v.u + 0x7FFFu + ((v.u >> 16) & 1u);   // RNE
    return (unsigned short)(r >> 16);
}
__device__ __forceinline__ float bf2f(unsigned short h) {
    union { unsigned u; float f; } v; v.u = ((unsigned)h) << 16; return v.f;
}
__device__ __forceinline__ void split3(float x, unsigned short* s) {
    unsigned short h = f2bf(x); float r = x - bf2f(h);
    unsigned short m = f2bf(r); float r2 = r - bf2f(m);
    s[0] = h; s[1] = m; s[2] = f2bf(r2);
}
__device__ __forceinline__ unsigned umin_(unsigned a, unsigned b) { return a < b ? a : b; }

// chunk-major record layout, XOR-swizzled; byte offset within the 32KB buffer
__device__ __forceinline__ int recaddr(int c, int row) {
    return (c << 13) + ((row << 4) ^ (c << 5));
}

// One block (512 thr) per bv. P (+2^-10 bias) via bf16-split MFMA; both argmin
// axes tracked as packed u32 keys (value-high-bits | index). Col-axis per-mt
// reduction is a balanced min3 tree in named scalars; bfr prefetched one mt
// ahead.
// LAUNCH BOUNDS HISTORY (do not tighten):
//   (512,8): 64-VGPR cap -> spill, FETCH 14->201MB, 112us  (round 5)
//   (512,6): allocator pins VGPR=40; tree+prefetch liveness ~80 -> spill,
//            FETCH 38MB WRITE 77MB, 48-50us               (rounds 7,8)
//   (512,4): grid gives only 2 blocks/CU = 4 waves/SIMD anyway -> cap 128,
//            no occupancy loss, no spill.                 (this round)
__global__ __launch_bounds__(512, 4)
void chamfer_bv(const float* __restrict__ achieved,
                const float* __restrict__ desired,
                float* __restrict__ rv_out)
{
    const int bv  = blockIdx.x;
    const int tid = threadIdx.x;

    __shared__ __align__(16) char buf[32768];     // A records, then B records,
                                                  // then rowKeyArr/cnt/red overlay
    __shared__ unsigned colKey[NN * 2];           // [m][lchk>>1]

    const float* arow = achieved + ((size_t)bv * NN + tid) * ND;
    const float* drow = desired  + ((size_t)bv * NN + tid) * ND;

    const unsigned short ONE = 0x3F80;
    const int pi[6] = {0,0,1,2,1,0};   // split-product pairs with i+j<=2
    const int pj[6] = {0,1,0,0,1,2};

    const float g5 = drow[5], g6 = drow[6], g7 = drow[7], g8 = drow[8];

    // ---- phase 1: A records (achieved; -2-scaled splits + sn2 + ONEs) ----
    {
        float a5 = arow[5], a6 = arow[6], a7 = arow[7], a8 = arow[8];
        unsigned short us[4][3];
        split3(-2.0f*a5, us[0]); split3(-2.0f*a6, us[1]);
        split3(-2.0f*a7, us[2]); split3(-2.0f*a8, us[3]);
        float sn2 = a5*a5 + a6*a6 + a7*a7 + a8*a8;
        unsigned short sn[3]; split3(sn2, sn);
        unsigned short t[32];
        #pragma unroll
        for (int d = 0; d < 4; ++d)
            #pragma unroll
            for (int p = 0; p < 6; ++p)
                t[d*6+p] = us[d][pi[p]];
        t[24]=sn[0]; t[25]=sn[1]; t[26]=sn[2];
        t[27]=ONE;   t[28]=ONE;   t[29]=ONE;
        t[30]=ONE;   t[31]=0;                       // pairs with bias in B
        #pragma unroll
        for (int c = 0; c < 4; ++c) {
            bf16x8 v;
            #pragma unroll
            for (int e = 0; e < 8; ++e) v[e] = (short)t[c*8+e];
            *(bf16x8*)(buf + recaddr(c, tid)) = v;
        }
    }
    colKey[tid*2]   = 0xFFFFFFFFu;
    colKey[tid*2+1] = 0xFFFFFFFFu;
    __syncthreads();

    const int lane = tid & 63, wid = tid >> 6;
    const int lrow = lane & 15, lchk = lane >> 4;

    bf16x8 afr[4];
    #pragma unroll
    for (int nt = 0; nt < 4; ++nt)
        afr[nt] = *(const bf16x8*)(buf + recaddr(lchk, (wid<<6) + (nt<<4) + lrow));
    __syncthreads();   // A region dead

    // ---- phase 2: B records (desired) overwrite the same buffer ----
    {
        unsigned short gs[4][3];
        split3(g5, gs[0]); split3(g6, gs[1]); split3(g7, gs[2]); split3(g8, gs[3]);
        float gn2 = g5*g5 + g6*g6 + g7*g7 + g8*g8;
        unsigned short gn[3]; split3(gn2, gn);
        unsigned short t[32];
        #pragma unroll
        for (int d = 0; d < 4; ++d)
            #pragma unroll
            for (int p = 0; p < 6; ++p)
                t[d*6+p] = gs[d][pj[p]];
        t[24]=ONE;   t[25]=ONE;   t[26]=ONE;
        t[27]=gn[0]; t[28]=gn[1]; t[29]=gn[2];
        t[30]=0x3A80; t[31]=0;                      // +2^-10 bias -> P strictly > 0
        #pragma unroll
        for (int c = 0; c < 4; ++c) {
            bf16x8 v;
            #pragma unroll
            for (int e = 0; e < 8; ++e) v[e] = (short)t[c*8+e];
            *(bf16x8*)(buf + recaddr(c, tid)) = v;
        }
    }
    __syncthreads();

    unsigned rowKey[4][4];
    int ncst[4][4];
    #pragma unroll
    for (int nt = 0; nt < 4; ++nt)
        #pragma unroll
        for (int j = 0; j < 4; ++j) {
            rowKey[nt][j] = 0xFFFFFFFFu;
            ncst[nt][j]   = (wid<<6) + (nt<<4) + (lchk<<2) + j;
        }

    const unsigned MASK = 0xFFFFFE00u;
    const f32x4 z = {0.0f, 0.0f, 0.0f, 0.0f};
    const int cslice = lchk >> 1;

    // ---- main loop: 32 m-tiles; prefetched bfr; scalar min-tree for col ----
    bf16x8 bfr = *(const bf16x8*)(buf + recaddr(lchk, lrow));   // mt = 0
    #pragma unroll 4
    for (int mt = 0; mt < 32; ++mt) {
        const int mtn = (mt + 1) & 31;   // wrapped: branchless prefetch
        bf16x8 bnext = *(const bf16x8*)(buf + recaddr(lchk, (mtn<<4) + lrow));
        const unsigned mcur = (unsigned)((mt<<4) + lrow);
        unsigned cp0, cp1, cp2, cp3;
        #pragma unroll
        for (int nt = 0; nt < 4; ++nt) {
            f32x4 acc = __builtin_amdgcn_mfma_f32_16x16x32_bf16(afr[nt], bfr, z, 0, 0, 0);
            unsigned b0 = __float_as_uint(acc[0]) & MASK;
            unsigned b1 = __float_as_uint(acc[1]) & MASK;
            unsigned b2 = __float_as_uint(acc[2]) & MASK;
            unsigned b3 = __float_as_uint(acc[3]) & MASK;
            rowKey[nt][0] = umin_(rowKey[nt][0], b0 | mcur);
            rowKey[nt][1] = umin_(rowKey[nt][1], b1 | mcur);
            rowKey[nt][2] = umin_(rowKey[nt][2], b2 | mcur);
            rowKey[nt][3] = umin_(rowKey[nt][3], b3 | mcur);
            unsigned k0 = b0 | (unsigned)ncst[nt][0];
            unsigned k1 = b1 | (unsigned)ncst[nt][1];
            unsigned k2 = b2 | (unsigned)ncst[nt][2];
            unsigned k3 = b3 | (unsigned)ncst[nt][3];
            unsigned cp = umin_(umin_(k0, k1), umin_(k2, k3));
            if (nt == 0) cp0 = cp; else if (nt == 1) cp1 = cp;
            else if (nt == 2) cp2 = cp; else cp3 = cp;
        }
        unsigned cv = umin_(umin_(cp0, cp1), umin_(cp2, cp3));
        atomicMin(&colKey[(mcur << 1) | cslice], cv);   // 2-way same-addr max
        bfr = bnext;
    }

    // ---- row combine across the 16 lrow lanes (registers only) ----
    #pragma unroll
    for (int nt = 0; nt < 4; ++nt) {
        #pragma unroll
        for (int j = 0; j < 4; ++j) {
            unsigned v = rowKey[nt][j];
            #pragma unroll
            for (int s = 1; s <= 8; s <<= 1)
                v = umin_(v, (unsigned)__shfl_xor((int)v, s));
            rowKey[nt][j] = v;
        }
    }
    __syncthreads();   // buf dead, colKey atomics complete

    // ---- overlay post-loop arrays into buf ----
    unsigned* rowKeyArr = (unsigned*)buf;          // [512]
    int*      cnt       = (int*)(buf + 2048);      // [512]: A low16, B high16
    float*    redF      = (float*)(buf + 4096);    // [16]
    int*      redI      = (int*)(buf + 4160);      // [16]

    if (lrow == 0) {
        #pragma unroll
        for (int nt = 0; nt < 4; ++nt)
            #pragma unroll
            for (int j = 0; j < 4; ++j)
                rowKeyArr[ncst[nt][j]] = rowKey[nt][j];
    }
    cnt[tid] = 0;
    __syncthreads();

    // ---- epilogue: thread tid owns goal m=tid (dir A) and state n=tid (dir B) ----
    const unsigned kA = umin_(colKey[tid*2], colKey[tid*2+1]);
    const unsigned kB = rowKeyArr[tid];
    const int miA = (int)(kA & 0x1FFu);
    const int miB = (int)(kB & 0x1FFu);
    const bool latA = __uint_as_float(kA & MASK) > THRESH_SQ;
    const bool latB = __uint_as_float(kB & MASK) > THRESH_SQ;
    if (!latA) atomicAdd(&cnt[miA], 1);
    if (!latB) atomicAdd(&cnt[miB], 0x10000);
    __syncthreads();

    float sumA = 0.0f, sumB = 0.0f;
    if (!latA) {
        const float* sp = achieved + ((size_t)bv * NN + miA) * ND;
        float dx = drow[0] - sp[0], dy = drow[1] - sp[1];
        float w = 1.0f / ((float)(cnt[miA] & 0xFFFF) + EPS_W);
        sumA = w * sqrtf(dx*dx + dy*dy);
    }
    if (!latB) {
        const float* gp = desired + ((size_t)bv * NN + miB) * ND;
        float dx = arow[0] - gp[0], dy = arow[1] - gp[1];
        float w = 1.0f / ((float)(((unsigned)cnt[miB]) >> 16) + EPS_W);
        sumB = w * sqrtf(dx*dx + dy*dy);
    }
    const int c0 = cnt[tid];
    int grpPk = ((c0 & 0xFFFF) ? 1 : 0) | ((((unsigned)c0) >> 16) ? 0x10000 : 0);
    int latPk = (latA ? 1 : 0) | (latB ? 2 : 0);

    #pragma unroll
    for (int off = 32; off > 0; off >>= 1) {
        sumA  += __shfl_down(sumA, off);
        sumB  += __shfl_down(sumB, off);
        grpPk += __shfl_down(grpPk, off);
        latPk |= __shfl_down(latPk, off);
    }
    if (lane == 0) {
        redF[wid*2] = sumA; redF[wid*2+1] = sumB;
        redI[wid*2] = grpPk; redI[wid*2+1] = latPk;
    }
    __syncthreads();
    if (tid == 0) {
        float sA = 0.0f, sB = 0.0f; int G = 0, L = 0;
        #pragma unroll
        for (int w2 = 0; w2 < 8; ++w2) {
            sA += redF[w2*2]; sB += redF[w2*2+1];
            G  += redI[w2*2]; L |= redI[w2*2+1];
        }
        float unmA = (L & 1) ? 1.0f : 0.0f;
        float unmB = (L & 2) ? 1.0f : 0.0f;
        float gA = (float)(G & 0xFFFF), gB = (float)(((unsigned)G) >> 16);
        float rA = -(sA + unmA) / fmaxf(gA + unmA, 1.0f);
        float rB = -(sB + unmB) / fmaxf(gB + unmB, 1.0f);
        rv_out[bv] = 0.5f * (rA + rB);
    }
}

// out[b] = mean over v
__global__ void chamfer_finalize(const float* __restrict__ rv, float* __restrict__ out)
{
    int b = blockIdx.x * 256 + threadIdx.x;
    if (b < NB) out[b] = 0.5f * (rv[2*b] + rv[2*b + 1]);
}

extern "C" void kernel_launch(void* const* d_in, const int* in_sizes, int n_in,
                              void* d_out, int out_size, void* d_ws, size_t ws_size,
                              hipStream_t stream)
{
    const float* achieved = (const float*)d_in[0];
    const float* desired  = (const float*)d_in[1];
    float* out = (float*)d_out;
    float* rv  = (float*)d_ws;   // 2 KB scratch

    chamfer_bv<<<NB * NV, 512, 0, stream>>>(achieved, desired, rv);
    chamfer_finalize<<<1, 256, 0, stream>>>(rv, out);
}